// Round 1
// baseline (358.387 us; speedup 1.0000x reference)
//
#include <hip/hip_runtime.h>
#include <cmath>
#include <cstdint>

#define NBATCH 16
#define HH 56
#define WW 56
#define CCH 256
#define NHEADS 8
#define HDIM 32
#define WSP 7
#define NWIN 128
#define LTOK 392
#define LP 416
#define NTOK 3136

typedef __attribute__((ext_vector_type(8))) __bf16 bf16x8;
typedef __attribute__((ext_vector_type(4))) float f32x4;

// ---------------------------------------------------------------- pack qkv
// One block per (window, head). Q scaled, K padded to 416 keys (zeros),
// V transposed to [d][key] via LDS.
__global__ __launch_bounds__(256) void pack_qkv(const float* __restrict__ qkv,
        __bf16* __restrict__ Qb, __bf16* __restrict__ Kb, __bf16* __restrict__ Vt) {
    const int wh = blockIdx.x;             // win*8 + h
    const int win = wh >> 3, h = wh & 7;
    const int b = win >> 3, wi = win & 7;
    const int tid = threadIdx.x;
    const float scale = 0.17677669529663687f;   // 32^-0.5
    __shared__ __bf16 vt_s[LTOK][HDIM + 1];
    const size_t plane = (size_t)NBATCH * NTOK * CCH;
    const float* qs = qkv;
    const float* ks = qkv + plane;
    const float* vs = qkv + 2 * plane;
    for (int idx = tid; idx < LTOK * HDIM; idx += 256) {
        int l = idx >> 5, d = idx & 31;
        int r = l / 7, c = l % 7;
        int token = r * WW + wi * WSP + c;
        size_t s = ((size_t)b * NTOK + token) * CCH + h * HDIM + d;
        Qb[((size_t)wh * LTOK + l) * HDIM + d] = (__bf16)(qs[s] * scale);
        Kb[((size_t)wh * LP + l) * HDIM + d] = (__bf16)(ks[s]);
        vt_s[l][d] = (__bf16)(vs[s]);
    }
    for (int idx = LTOK * HDIM + tid; idx < LP * HDIM; idx += 256) {
        int l = idx >> 5, d = idx & 31;
        Kb[((size_t)wh * LP + l) * HDIM + d] = (__bf16)0.0f;
    }
    __syncthreads();
    for (int idx = tid; idx < HDIM * LP; idx += 256) {
        int d = idx / LP, l = idx % LP;
        Vt[((size_t)wh * HDIM + d) * LP + l] = (l < LTOK) ? vt_s[l][d] : (__bf16)0.0f;
    }
}

// ---------------------------------------------------------------- pack W
// HWIO (ky,kx,ci,co) fp32 -> [tap][co][ci] bf16 (contiguous ci for B-frags)
__global__ __launch_bounds__(256) void pack_w(const float* __restrict__ w,
                                              __bf16* __restrict__ Wt) {
    int idx = blockIdx.x * blockDim.x + threadIdx.x;
    if (idx >= 9 * CCH * CCH) return;
    int tap = idx / (CCH * CCH);
    int rem = idx % (CCH * CCH);
    int co = rem / CCH, ci = rem % CCH;
    Wt[idx] = (__bf16)(w[(size_t)tap * CCH * CCH + (size_t)ci * CCH + co]);
}

// ---------------------------------------------------------------- LePE conv
// Implicit GEMM. Block = (window, 8-row stripe): M=56 pos (padded 64), N=256.
// A tile: halo rows staged in LDS [10][9][264] (zero-padded cols, padded stride).
#define AV_R 10
#define AV_C 9
#define AV_S 264
__global__ __launch_bounds__(256) void lepe_conv(const float* __restrict__ qkv,
        const __bf16* __restrict__ Wt, const float* __restrict__ bconv,
        float* __restrict__ out) {
    const int bid = blockIdx.x;
    const int win = bid / 7, rb = bid % 7;
    const int b = win >> 3, wi = win & 7;
    const int rbase = rb * 8;
    const int tid = threadIdx.x;
    const int lane = tid & 63, wv = tid >> 6;
    const int lr = lane & 15, lg = lane >> 4;
    __shared__ __bf16 Av[AV_R * AV_C * AV_S];
    const float* vsrc = qkv + 2 * (size_t)NBATCH * NTOK * CCH;

    for (int t = tid; t < AV_R * 7 * 64; t += 256) {
        int rr = t / (7 * 64);
        int rem = t % (7 * 64);
        int c = rem / 64, chg = rem % 64;
        int ar = rbase + rr - 1;
        f32x4 v = {0.f, 0.f, 0.f, 0.f};
        if (ar >= 0 && ar < HH) {
            int token = ar * WW + wi * WSP + c;
            v = *(const f32x4*)(vsrc + ((size_t)b * NTOK + token) * CCH + chg * 4);
        }
        __bf16* dst = &Av[(rr * AV_C + (c + 1)) * AV_S + chg * 4];
        dst[0] = (__bf16)v[0]; dst[1] = (__bf16)v[1];
        dst[2] = (__bf16)v[2]; dst[3] = (__bf16)v[3];
    }
    for (int t = tid; t < AV_R * 64; t += 256) {        // zero halo columns
        int rr = t / 64, chg = t % 64;
        __bf16* d0 = &Av[(rr * AV_C + 0) * AV_S + chg * 4];
        __bf16* d8 = &Av[(rr * AV_C + 8) * AV_S + chg * 4];
        d0[0] = d0[1] = d0[2] = d0[3] = (__bf16)0.0f;
        d8[0] = d8[1] = d8[2] = d8[3] = (__bf16)0.0f;
    }
    __syncthreads();

    f32x4 acc[4][4];
#pragma unroll
    for (int i = 0; i < 4; i++)
#pragma unroll
        for (int j = 0; j < 4; j++) acc[i][j] = (f32x4){0.f, 0.f, 0.f, 0.f};

    int rrb[4], ccb[4];
#pragma unroll
    for (int mt = 0; mt < 4; mt++) {
        int p = mt * 16 + lr; if (p > 55) p = 55;
        rrb[mt] = p / 7; ccb[mt] = p % 7;
    }
    for (int tap = 0; tap < 9; tap++) {
        const int dy = tap / 3, dx = tap % 3;
#pragma unroll
        for (int ks = 0; ks < 8; ks++) {
            bf16x8 a[4], bb[4];
#pragma unroll
            for (int mt = 0; mt < 4; mt++) {
                int addr = ((rrb[mt] + dy) * AV_C + (ccb[mt] + dx)) * AV_S + ks * 32 + lg * 8;
                a[mt] = *(const bf16x8*)&Av[addr];
            }
#pragma unroll
            for (int nt = 0; nt < 4; nt++) {
                int co = wv * 64 + nt * 16 + lr;
                bb[nt] = *(const bf16x8*)(Wt + ((size_t)tap * CCH + co) * CCH + ks * 32 + lg * 8);
            }
#pragma unroll
            for (int mt = 0; mt < 4; mt++)
#pragma unroll
                for (int nt = 0; nt < 4; nt++)
                    acc[mt][nt] = __builtin_amdgcn_mfma_f32_16x16x32_bf16(
                        a[mt], bb[nt], acc[mt][nt], 0, 0, 0);
        }
    }
#pragma unroll
    for (int nt = 0; nt < 4; nt++) {
        int ch = wv * 64 + nt * 16 + lr;
        float bias = bconv[ch];
#pragma unroll
        for (int mt = 0; mt < 4; mt++) {
#pragma unroll
            for (int r = 0; r < 4; r++) {
                int p = mt * 16 + lg * 4 + r;
                if (p < 56) {
                    int ar = rbase + p / 7, c = p % 7;
                    int token = ar * WW + wi * WSP + c;
                    out[((size_t)b * NTOK + token) * CCH + ch] = acc[mt][nt][r] + bias;
                }
            }
        }
    }
}

// ---------------------------------------------------------------- attention
// Block = (win-head, 64-q-row block). 4 waves x 16 q-rows. S in registers,
// softmax via shfl within 16-lane groups, P->A-frag via per-wave LDS bounce.
#define KS_S 36
#define VS_S 424
#define PB_S 40
__global__ __launch_bounds__(256) void attn(const __bf16* __restrict__ Qb,
        const __bf16* __restrict__ Kb, const __bf16* __restrict__ Vt,
        float* __restrict__ out) {
    const int bid = blockIdx.x;
    const int wh = bid / 7, mb = bid % 7;
    const int win = wh >> 3, h = wh & 7;
    const int b = win >> 3, wi = win & 7;
    const int tid = threadIdx.x;
    const int lane = tid & 63, wv = tid >> 6;
    const int lr = lane & 15, lg = lane >> 4;
    __shared__ __bf16 Ks[LP * KS_S];
    __shared__ __bf16 Vs[HDIM * VS_S];
    __shared__ __bf16 Pb[4][16 * PB_S];

    for (int t = tid; t < LP * 4; t += 256) {
        int row = t >> 2, g = t & 3;
        *(bf16x8*)&Ks[row * KS_S + g * 8] =
            *(const bf16x8*)&Kb[((size_t)wh * LP + row) * HDIM + g * 8];
    }
    for (int t = tid; t < HDIM * 52; t += 256) {
        int row = t / 52, g = t % 52;
        *(bf16x8*)&Vs[row * VS_S + g * 8] =
            *(const bf16x8*)&Vt[((size_t)wh * HDIM + row) * LP + g * 8];
    }
    int qrow = mb * 64 + wv * 16 + lr;
    int qe = qrow < LTOK ? qrow : LTOK - 1;
    bf16x8 aq = *(const bf16x8*)&Qb[((size_t)wh * LTOK + qe) * HDIM + lg * 8];
    __syncthreads();

    f32x4 s[26];
#pragma unroll
    for (int t = 0; t < 25; t++) {
        bf16x8 bk = *(const bf16x8*)&Ks[(t * 16 + lr) * KS_S + lg * 8];
        s[t] = __builtin_amdgcn_mfma_f32_16x16x32_bf16(
            aq, bk, (f32x4){0.f, 0.f, 0.f, 0.f}, 0, 0, 0);
    }
#pragma unroll
    for (int r = 0; r < 4; r++) s[25][r] = -INFINITY;
    if (lr >= 8) {
#pragma unroll
        for (int r = 0; r < 4; r++) s[24][r] = -INFINITY;   // keys 392..399
    }
    float inv[4];
#pragma unroll
    for (int r = 0; r < 4; r++) {
        float m = s[0][r];
#pragma unroll
        for (int t = 1; t < 25; t++) m = fmaxf(m, s[t][r]);
#pragma unroll
        for (int off = 1; off < 16; off <<= 1) m = fmaxf(m, __shfl_xor(m, off, 64));
        float sum = 0.f;
#pragma unroll
        for (int t = 0; t < 26; t++) {
            float e = __expf(s[t][r] - m);
            s[t][r] = e;
            sum += e;
        }
#pragma unroll
        for (int off = 1; off < 16; off <<= 1) sum += __shfl_xor(sum, off, 64);
        inv[r] = 1.0f / sum;
    }
    // PV: 13 chunks of 32 keys, per-wave LDS bounce for P transpose
    f32x4 xacc[2] = {{0.f, 0.f, 0.f, 0.f}, {0.f, 0.f, 0.f, 0.f}};
    __bf16* pb = Pb[wv];
    for (int j = 0; j < 13; j++) {
#pragma unroll
        for (int half = 0; half < 2; half++) {
            int t = 2 * j + half;
#pragma unroll
            for (int r = 0; r < 4; r++)
                pb[(lg * 4 + r) * PB_S + half * 16 + lr] = (__bf16)s[t][r];
        }
        asm volatile("s_waitcnt lgkmcnt(0)" ::: "memory");
        __builtin_amdgcn_sched_barrier(0);
        bf16x8 ap = *(const bf16x8*)&pb[lr * PB_S + lg * 8];
#pragma unroll
        for (int nt = 0; nt < 2; nt++) {
            bf16x8 bv = *(const bf16x8*)&Vs[(nt * 16 + lr) * VS_S + j * 32 + lg * 8];
            xacc[nt] = __builtin_amdgcn_mfma_f32_16x16x32_bf16(ap, bv, xacc[nt], 0, 0, 0);
        }
        __builtin_amdgcn_sched_barrier(0);
    }
    int qrow0 = mb * 64 + wv * 16;
#pragma unroll
    for (int r = 0; r < 4; r++) {
        int q = qrow0 + lg * 4 + r;
        if (q < LTOK) {
            int rI = q / 7, c = q % 7;
            size_t base = ((size_t)b * NTOK + rI * WW + wi * WSP + c) * CCH + h * HDIM;
#pragma unroll
            for (int nt = 0; nt < 2; nt++)
                out[base + nt * 16 + lr] += xacc[nt][r] * inv[r];
        }
    }
}

// ---------------------------------------------------------------- launch
extern "C" void kernel_launch(void* const* d_in, const int* in_sizes, int n_in,
                              void* d_out, int out_size, void* d_ws, size_t ws_size,
                              hipStream_t stream) {
    const float* qkv = (const float*)d_in[0];
    const float* wconv = (const float*)d_in[1];
    const float* bconv = (const float*)d_in[2];
    float* out = (float*)d_out;
    char* ws = (char*)d_ws;

    const size_t QB_BYTES = (size_t)NWIN * NHEADS * LTOK * HDIM * 2;   // 25,690,112
    const size_t KB_BYTES = (size_t)NWIN * NHEADS * LP * HDIM * 2;     // 27,262,976
    const size_t VT_BYTES = KB_BYTES;
    const size_t WT_BYTES = (size_t)9 * CCH * CCH * 2;
    if (ws_size < QB_BYTES + KB_BYTES + VT_BYTES + WT_BYTES) return;

    __bf16* Qb = (__bf16*)ws;
    __bf16* Kb = (__bf16*)(ws + QB_BYTES);
    __bf16* Vt = (__bf16*)(ws + QB_BYTES + KB_BYTES);
    __bf16* Wt = (__bf16*)(ws + QB_BYTES + KB_BYTES + VT_BYTES);

    pack_qkv<<<NWIN * NHEADS, 256, 0, stream>>>(qkv, Qb, Kb, Vt);
    pack_w<<<(9 * CCH * CCH + 255) / 256, 256, 0, stream>>>(wconv, Wt);
    lepe_conv<<<NWIN * 7, 256, 0, stream>>>(qkv, Wt, bconv, out);
    attn<<<NWIN * NHEADS * 7, 256, 0, stream>>>(Qb, Kb, Vt, out);
}

// Round 2
// 256.363 us; speedup vs baseline: 1.3980x; 1.3980x over previous
//
#include <hip/hip_runtime.h>
#include <cmath>
#include <cstdint>

#define NBATCH 16
#define HH 56
#define WW 56
#define CCH 256
#define NHEADS 8
#define HDIM 32
#define WSP 7
#define NWIN 128
#define LTOK 392
#define NTOK 3136

typedef __attribute__((ext_vector_type(8))) __bf16 bf16x8;
typedef __attribute__((ext_vector_type(4))) __bf16 bf16x4;
typedef __attribute__((ext_vector_type(4))) float f32x4;

// ---------------------------------------------------------------- pack W
// HWIO (ky,kx,ci,co) fp32 -> [tap][co][ci] bf16 (contiguous ci for B-frags)
__global__ __launch_bounds__(256) void pack_w(const float* __restrict__ w,
                                              __bf16* __restrict__ Wt) {
    int idx = blockIdx.x * blockDim.x + threadIdx.x;
    if (idx >= 9 * CCH * CCH) return;
    int tap = idx / (CCH * CCH);
    int rem = idx % (CCH * CCH);
    int co = rem / CCH, ci = rem % CCH;
    Wt[idx] = (__bf16)(w[(size_t)tap * CCH * CCH + (size_t)ci * CCH + co]);
}

// ---------------------------------------------------------------- LePE conv
// Implicit GEMM. Block = (window, 8-row stripe): M=56 pos (padded 64), N=256.
// A tile: halo rows staged in LDS [10][9][264] (zero-padded cols, padded stride).
#define AV_R 10
#define AV_C 9
#define AV_S 264
__global__ __launch_bounds__(256) void lepe_conv(const float* __restrict__ qkv,
        const __bf16* __restrict__ Wt, const float* __restrict__ bconv,
        float* __restrict__ out) {
    const int bid = blockIdx.x;
    const int win = bid / 7, rb = bid % 7;
    const int b = win >> 3, wi = win & 7;
    const int rbase = rb * 8;
    const int tid = threadIdx.x;
    const int lane = tid & 63, wv = tid >> 6;
    const int lr = lane & 15, lg = lane >> 4;
    __shared__ __bf16 Av[AV_R * AV_C * AV_S];
    const float* vsrc = qkv + 2 * (size_t)NBATCH * NTOK * CCH;

    for (int t = tid; t < AV_R * 7 * 64; t += 256) {
        int rr = t / (7 * 64);
        int rem = t % (7 * 64);
        int c = rem / 64, chg = rem % 64;
        int ar = rbase + rr - 1;
        f32x4 v = {0.f, 0.f, 0.f, 0.f};
        if (ar >= 0 && ar < HH) {
            int token = ar * WW + wi * WSP + c;
            v = *(const f32x4*)(vsrc + ((size_t)b * NTOK + token) * CCH + chg * 4);
        }
        __bf16* dst = &Av[(rr * AV_C + (c + 1)) * AV_S + chg * 4];
        dst[0] = (__bf16)v[0]; dst[1] = (__bf16)v[1];
        dst[2] = (__bf16)v[2]; dst[3] = (__bf16)v[3];
    }
    for (int t = tid; t < AV_R * 64; t += 256) {        // zero halo columns
        int rr = t / 64, chg = t % 64;
        __bf16* d0 = &Av[(rr * AV_C + 0) * AV_S + chg * 4];
        __bf16* d8 = &Av[(rr * AV_C + 8) * AV_S + chg * 4];
        d0[0] = d0[1] = d0[2] = d0[3] = (__bf16)0.0f;
        d8[0] = d8[1] = d8[2] = d8[3] = (__bf16)0.0f;
    }
    __syncthreads();

    f32x4 acc[4][4];
#pragma unroll
    for (int i = 0; i < 4; i++)
#pragma unroll
        for (int j = 0; j < 4; j++) acc[i][j] = (f32x4){0.f, 0.f, 0.f, 0.f};

    int rrb[4], ccb[4];
#pragma unroll
    for (int mt = 0; mt < 4; mt++) {
        int p = mt * 16 + lr; if (p > 55) p = 55;
        rrb[mt] = p / 7; ccb[mt] = p % 7;
    }
    for (int tap = 0; tap < 9; tap++) {
        const int dy = tap / 3, dx = tap % 3;
#pragma unroll
        for (int ks = 0; ks < 8; ks++) {
            bf16x8 a[4], bb[4];
#pragma unroll
            for (int mt = 0; mt < 4; mt++) {
                int addr = ((rrb[mt] + dy) * AV_C + (ccb[mt] + dx)) * AV_S + ks * 32 + lg * 8;
                a[mt] = *(const bf16x8*)&Av[addr];
            }
#pragma unroll
            for (int nt = 0; nt < 4; nt++) {
                int co = wv * 64 + nt * 16 + lr;
                bb[nt] = *(const bf16x8*)(Wt + ((size_t)tap * CCH + co) * CCH + ks * 32 + lg * 8);
            }
#pragma unroll
            for (int mt = 0; mt < 4; mt++)
#pragma unroll
                for (int nt = 0; nt < 4; nt++)
                    acc[mt][nt] = __builtin_amdgcn_mfma_f32_16x16x32_bf16(
                        a[mt], bb[nt], acc[mt][nt], 0, 0, 0);
        }
    }
#pragma unroll
    for (int nt = 0; nt < 4; nt++) {
        int ch = wv * 64 + nt * 16 + lr;
        float bias = bconv[ch];
#pragma unroll
        for (int mt = 0; mt < 4; mt++) {
#pragma unroll
            for (int r = 0; r < 4; r++) {
                int p = mt * 16 + lg * 4 + r;
                if (p < 56) {
                    int ar = rbase + p / 7, c = p % 7;
                    int token = ar * WW + wi * WSP + c;
                    out[((size_t)b * NTOK + token) * CCH + ch] = acc[mt][nt][r] + bias;
                }
            }
        }
    }
}

// ---------------------------------------------------------------- attention
// One block per (win, head). 8 waves. K (zero-padded to 400 rows) and V^T
// staged ONCE from f32 qkv with fused bf16 conversion; each wave sweeps
// q-tiles {wv, wv+8, wv+16, wv+24}. S in registers, softmax via shfl within
// 16-lane groups, P->A-frag via per-wave LDS bounce (stride 36, 2x b64 read).
#define KS_R 400
#define KS_S 36
#define VS_S 424
#define PB_S 36
__global__ __launch_bounds__(512, 4) void attn2(const float* __restrict__ qkv,
                                                float* __restrict__ out) {
    const int wh = blockIdx.x;
    const int win = wh >> 3, h = wh & 7;
    const int b = win >> 3, wi = win & 7;
    const int tid = threadIdx.x;
    const int lane = tid & 63, wv = tid >> 6;
    const int lr = lane & 15, lg = lane >> 4;
    const float scale = 0.17677669529663687f;   // 32^-0.5

    __shared__ __bf16 Ks[KS_R * KS_S];          // 28,800 B
    __shared__ __bf16 Vs[HDIM * VS_S];          // 27,136 B
    __shared__ __bf16 Pb[8][16 * PB_S];         //  9,216 B  (total 65,152)

    const size_t plane = (size_t)NBATCH * NTOK * CCH;
    const float* qsrc = qkv + ((size_t)b * NTOK) * CCH + h * HDIM;
    const float* ksrc = qsrc + plane;
    const float* vsrc = qsrc + 2 * plane;

    // ---- stage K: [400 rows][32 ch], rows >=392 zero
    for (int t = tid; t < KS_R * 4; t += 512) {
        int row = t >> 2, g = t & 3;
        bf16x8 val;
        if (row < LTOK) {
            int tok = (row / 7) * WW + wi * WSP + row % 7;
            const float* p = ksrc + (size_t)tok * CCH + g * 8;
            f32x4 a = *(const f32x4*)p;
            f32x4 c = *(const f32x4*)(p + 4);
#pragma unroll
            for (int i = 0; i < 4; i++) { val[i] = (__bf16)a[i]; val[4 + i] = (__bf16)c[i]; }
        } else {
#pragma unroll
            for (int i = 0; i < 8; i++) val[i] = (__bf16)0.0f;
        }
        *(bf16x8*)&Ks[row * KS_S + g * 8] = val;
    }
    // ---- stage V transposed: Vs[ch][key]
    for (int t = tid; t < LTOK * 4; t += 512) {
        int key = t % LTOK, chg = t / LTOK;
        int tok = (key / 7) * WW + wi * WSP + key % 7;
        const float* p = vsrc + (size_t)tok * CCH + chg * 8;
        f32x4 a = *(const f32x4*)p;
        f32x4 c = *(const f32x4*)(p + 4);
#pragma unroll
        for (int i = 0; i < 4; i++) {
            Vs[(chg * 8 + i) * VS_S + key] = (__bf16)a[i];
            Vs[(chg * 8 + 4 + i) * VS_S + key] = (__bf16)c[i];
        }
    }
    // zero V pad keys 392..423
    for (int t = tid; t < HDIM * 32; t += 512) {
        int ch = t >> 5, k = t & 31;
        Vs[ch * VS_S + LTOK + k] = (__bf16)0.0f;
    }
    __syncthreads();

    __bf16* pb = Pb[wv];
    for (int tile = wv; tile < 25; tile += 8) {
        // ---- load Q fragment direct from f32 (scaled)
        int qrow = tile * 16 + lr;
        int qe = qrow < LTOK ? qrow : LTOK - 1;
        int tokq = (qe / 7) * WW + wi * WSP + qe % 7;
        const float* qp = qsrc + (size_t)tokq * CCH + lg * 8;
        f32x4 qa = *(const f32x4*)qp;
        f32x4 qc = *(const f32x4*)(qp + 4);
        bf16x8 aq;
#pragma unroll
        for (int i = 0; i < 4; i++) {
            aq[i] = (__bf16)(qa[i] * scale);
            aq[4 + i] = (__bf16)(qc[i] * scale);
        }

        // ---- S = Q K^T  (25 key tiles of 16)
        f32x4 s[26];
#pragma unroll
        for (int t = 0; t < 25; t++) {
            bf16x8 bk = *(const bf16x8*)&Ks[(t * 16 + lr) * KS_S + lg * 8];
            s[t] = __builtin_amdgcn_mfma_f32_16x16x32_bf16(
                aq, bk, (f32x4){0.f, 0.f, 0.f, 0.f}, 0, 0, 0);
        }
#pragma unroll
        for (int r = 0; r < 4; r++) s[25][r] = -INFINITY;
        if (lr >= 8) {
#pragma unroll
            for (int r = 0; r < 4; r++) s[24][r] = -INFINITY;   // keys 392..399
        }
        // ---- softmax (rows are (lg*4+r), reduce across lr lanes)
        float inv[4];
#pragma unroll
        for (int r = 0; r < 4; r++) {
            float m = s[0][r];
#pragma unroll
            for (int t = 1; t < 25; t++) m = fmaxf(m, s[t][r]);
#pragma unroll
            for (int off = 1; off < 16; off <<= 1) m = fmaxf(m, __shfl_xor(m, off, 64));
            float sum = 0.f;
#pragma unroll
            for (int t = 0; t < 26; t++) {
                float e = __expf(s[t][r] - m);
                s[t][r] = e;
                sum += e;
            }
#pragma unroll
            for (int off = 1; off < 16; off <<= 1) sum += __shfl_xor(sum, off, 64);
            inv[r] = 1.0f / sum;
        }
        // ---- PV: 13 chunks of 32 keys, per-wave LDS bounce for P transpose
        f32x4 xacc[2] = {{0.f, 0.f, 0.f, 0.f}, {0.f, 0.f, 0.f, 0.f}};
        for (int j = 0; j < 13; j++) {
#pragma unroll
            for (int half = 0; half < 2; half++) {
                int t = 2 * j + half;
#pragma unroll
                for (int r = 0; r < 4; r++)
                    pb[(lg * 4 + r) * PB_S + half * 16 + lr] = (__bf16)s[t][r];
            }
            asm volatile("s_waitcnt lgkmcnt(0)" ::: "memory");
            __builtin_amdgcn_sched_barrier(0);
            bf16x4 lo = *(const bf16x4*)&pb[lr * PB_S + lg * 8];
            bf16x4 hi = *(const bf16x4*)&pb[lr * PB_S + lg * 8 + 4];
            bf16x8 ap;
#pragma unroll
            for (int i = 0; i < 4; i++) { ap[i] = lo[i]; ap[4 + i] = hi[i]; }
#pragma unroll
            for (int nt = 0; nt < 2; nt++) {
                bf16x8 bv = *(const bf16x8*)&Vs[(nt * 16 + lr) * VS_S + j * 32 + lg * 8];
                xacc[nt] = __builtin_amdgcn_mfma_f32_16x16x32_bf16(ap, bv, xacc[nt], 0, 0, 0);
            }
            __builtin_amdgcn_sched_barrier(0);
        }
        // ---- write out (RMW add onto conv output)
#pragma unroll
        for (int r = 0; r < 4; r++) {
            int q = tile * 16 + lg * 4 + r;
            if (q < LTOK) {
                int rI = q / 7, c = q % 7;
                size_t base = ((size_t)b * NTOK + rI * WW + wi * WSP + c) * CCH + h * HDIM;
#pragma unroll
                for (int nt = 0; nt < 2; nt++)
                    out[base + nt * 16 + lr] += xacc[nt][r] * inv[r];
            }
        }
    }
}

// ---------------------------------------------------------------- launch
extern "C" void kernel_launch(void* const* d_in, const int* in_sizes, int n_in,
                              void* d_out, int out_size, void* d_ws, size_t ws_size,
                              hipStream_t stream) {
    const float* qkv = (const float*)d_in[0];
    const float* wconv = (const float*)d_in[1];
    const float* bconv = (const float*)d_in[2];
    float* out = (float*)d_out;
    char* ws = (char*)d_ws;

    const size_t WT_BYTES = (size_t)9 * CCH * CCH * 2;
    if (ws_size < WT_BYTES) return;
    __bf16* Wt = (__bf16*)ws;

    pack_w<<<(9 * CCH * CCH + 255) / 256, 256, 0, stream>>>(wconv, Wt);
    lepe_conv<<<NWIN * 7, 256, 0, stream>>>(qkv, Wt, bconv, out);
    attn2<<<NWIN * NHEADS, 512, 0, stream>>>(qkv, out);
}

// Round 3
// 248.355 us; speedup vs baseline: 1.4430x; 1.0322x over previous
//
#include <hip/hip_runtime.h>
#include <cmath>
#include <cstdint>

#define NBATCH 16
#define HH 56
#define WW 56
#define CCH 256
#define NHEADS 8
#define HDIM 32
#define WSP 7
#define NWIN 128
#define LTOK 392
#define NTOK 3136

typedef __attribute__((ext_vector_type(8))) __bf16 bf16x8;
typedef __attribute__((ext_vector_type(4))) __bf16 bf16x4;
typedef __attribute__((ext_vector_type(4))) float f32x4;

// ---------------------------------------------------------------- pack W
// HWIO (ky,kx,ci,co) fp32 -> [tap][co][ci] bf16 (contiguous ci for B-frags)
__global__ __launch_bounds__(256) void pack_w(const float* __restrict__ w,
                                              __bf16* __restrict__ Wt) {
    int idx = blockIdx.x * blockDim.x + threadIdx.x;
    if (idx >= 9 * CCH * CCH) return;
    int tap = idx / (CCH * CCH);
    int rem = idx % (CCH * CCH);
    int co = rem / CCH, ci = rem % CCH;
    Wt[idx] = (__bf16)(w[(size_t)tap * CCH * CCH + (size_t)ci * CCH + co]);
}

// ---------------------------------------------------------------- LePE conv
// Implicit GEMM. Block = (window, 8-row stripe): M=56 pos (padded 64), N=256.
// A tile: halo rows staged in LDS [10][9][264]. B (weights) software-pipelined
// through a register double-buffer across the flattened 72-step K loop.
#define AV_R 10
#define AV_C 9
#define AV_S 264
__global__ __launch_bounds__(256, 3) void lepe_conv(const float* __restrict__ qkv,
        const __bf16* __restrict__ Wt, const float* __restrict__ bconv,
        float* __restrict__ out) {
    const int bid = blockIdx.x;
    const int win = bid / 7, rb = bid % 7;
    const int b = win >> 3, wi = win & 7;
    const int rbase = rb * 8;
    const int tid = threadIdx.x;
    const int lane = tid & 63, wv = tid >> 6;
    const int lr = lane & 15, lg = lane >> 4;
    __shared__ __bf16 Av[AV_R * AV_C * AV_S];
    const float* vsrc = qkv + 2 * (size_t)NBATCH * NTOK * CCH;

    // ---- stage A (V window rows + halo), one fused pass, 8B LDS writes
    for (int t = tid; t < AV_R * AV_C * 64; t += 256) {
        int rr = t / (AV_C * 64);
        int rem = t % (AV_C * 64);
        int cc = rem / 64, chg = rem % 64;
        int ar = rbase + rr - 1, c = cc - 1;
        f32x4 v = {0.f, 0.f, 0.f, 0.f};
        if (ar >= 0 && ar < HH && c >= 0 && c < WSP) {
            int token = ar * WW + wi * WSP + c;
            v = *(const f32x4*)(vsrc + ((size_t)b * NTOK + token) * CCH + chg * 4);
        }
        bf16x4 w;
#pragma unroll
        for (int i = 0; i < 4; i++) w[i] = (__bf16)v[i];
        *(bf16x4*)&Av[(rr * AV_C + cc) * AV_S + chg * 4] = w;
    }
    __syncthreads();

    f32x4 acc[4][4];
#pragma unroll
    for (int i = 0; i < 4; i++)
#pragma unroll
        for (int j = 0; j < 4; j++) acc[i][j] = (f32x4){0.f, 0.f, 0.f, 0.f};

    // per-thread constant bases
    int ab[4];
#pragma unroll
    for (int mt = 0; mt < 4; mt++) {
        int p = mt * 16 + lr; if (p > 55) p = 55;
        ab[mt] = ((p / 7) * AV_C + (p % 7)) * AV_S + lg * 8;
    }
    const __bf16* wb[4];
#pragma unroll
    for (int nt = 0; nt < 4; nt++)
        wb[nt] = Wt + (size_t)(wv * 64 + nt * 16 + lr) * CCH + lg * 8;

#define LOADB(dst, s) do {                                                  \
        const int tap_ = (s) >> 3, ks_ = (s) & 7;                           \
        const int offw = tap_ * (CCH * CCH) + ks_ * 32;                     \
        _Pragma("unroll")                                                   \
        for (int nt = 0; nt < 4; nt++)                                      \
            dst[nt] = *(const bf16x8*)(wb[nt] + offw);                      \
    } while (0)

#define STEPM(bR, s) do {                                                   \
        const int tap_ = (s) >> 3, ks_ = (s) & 7;                           \
        const int dy_ = (tap_ >= 6) ? 2 : ((tap_ >= 3) ? 1 : 0);            \
        const int offa = (tap_ + 6 * dy_) * AV_S + ks_ * 32;                \
        bf16x8 a_[4];                                                       \
        _Pragma("unroll")                                                   \
        for (int mt = 0; mt < 4; mt++)                                      \
            a_[mt] = *(const bf16x8*)&Av[ab[mt] + offa];                    \
        _Pragma("unroll")                                                   \
        for (int mt = 0; mt < 4; mt++)                                      \
            _Pragma("unroll")                                               \
            for (int nt = 0; nt < 4; nt++)                                  \
                acc[mt][nt] = __builtin_amdgcn_mfma_f32_16x16x32_bf16(      \
                    a_[mt], bR[nt], acc[mt][nt], 0, 0, 0);                  \
    } while (0)

    bf16x8 bA[4], bB[4];
    LOADB(bA, 0);
    for (int s = 0; s < 72; s += 2) {
        LOADB(bB, s + 1);
        STEPM(bA, s);
        if (s < 70) LOADB(bA, s + 2);
        STEPM(bB, s + 1);
    }
#undef LOADB
#undef STEPM

#pragma unroll
    for (int nt = 0; nt < 4; nt++) {
        int ch = wv * 64 + nt * 16 + lr;
        float bias = bconv[ch];
#pragma unroll
        for (int mt = 0; mt < 4; mt++) {
#pragma unroll
            for (int r = 0; r < 4; r++) {
                int p = mt * 16 + lg * 4 + r;
                if (p < 56) {
                    int ar = rbase + p / 7, c = p % 7;
                    int token = ar * WW + wi * WSP + c;
                    out[((size_t)b * NTOK + token) * CCH + ch] = acc[mt][nt][r] + bias;
                }
            }
        }
    }
}

// ---------------------------------------------------------------- attention
// One block per (win, head). 8 waves. K (zero-padded to 400 rows) and V^T
// staged ONCE from f32 qkv with fused bf16 conversion; each wave sweeps
// q-tiles {wv, wv+8, wv+16, wv+24}. S in registers, softmax via shfl within
// 16-lane groups, P->A-frag via per-wave LDS bounce (stride 36, 2x b64 read).
#define KS_R 400
#define KS_S 36
#define VS_S 424
#define PB_S 36
__global__ __launch_bounds__(512, 4) void attn2(const float* __restrict__ qkv,
                                                float* __restrict__ out) {
    const int wh = blockIdx.x;
    const int win = wh >> 3, h = wh & 7;
    const int b = win >> 3, wi = win & 7;
    const int tid = threadIdx.x;
    const int lane = tid & 63, wv = tid >> 6;
    const int lr = lane & 15, lg = lane >> 4;
    const float scale = 0.17677669529663687f;   // 32^-0.5

    __shared__ __bf16 Ks[KS_R * KS_S];          // 28,800 B
    __shared__ __bf16 Vs[HDIM * VS_S];          // 27,136 B
    __shared__ __bf16 Pb[8][16 * PB_S];         //  9,216 B  (total 65,152)

    const size_t plane = (size_t)NBATCH * NTOK * CCH;
    const float* qsrc = qkv + ((size_t)b * NTOK) * CCH + h * HDIM;
    const float* ksrc = qsrc + plane;
    const float* vsrc = qsrc + 2 * plane;

    // ---- stage K: [400 rows][32 ch], rows >=392 zero
    for (int t = tid; t < KS_R * 4; t += 512) {
        int row = t >> 2, g = t & 3;
        bf16x8 val;
        if (row < LTOK) {
            int tok = (row / 7) * WW + wi * WSP + row % 7;
            const float* p = ksrc + (size_t)tok * CCH + g * 8;
            f32x4 a = *(const f32x4*)p;
            f32x4 c = *(const f32x4*)(p + 4);
#pragma unroll
            for (int i = 0; i < 4; i++) { val[i] = (__bf16)a[i]; val[4 + i] = (__bf16)c[i]; }
        } else {
#pragma unroll
            for (int i = 0; i < 8; i++) val[i] = (__bf16)0.0f;
        }
        *(bf16x8*)&Ks[row * KS_S + g * 8] = val;
    }
    // ---- stage V transposed: Vs[ch][key]
    for (int t = tid; t < LTOK * 4; t += 512) {
        int key = t % LTOK, chg = t / LTOK;
        int tok = (key / 7) * WW + wi * WSP + key % 7;
        const float* p = vsrc + (size_t)tok * CCH + chg * 8;
        f32x4 a = *(const f32x4*)p;
        f32x4 c = *(const f32x4*)(p + 4);
#pragma unroll
        for (int i = 0; i < 4; i++) {
            Vs[(chg * 8 + i) * VS_S + key] = (__bf16)a[i];
            Vs[(chg * 8 + 4 + i) * VS_S + key] = (__bf16)c[i];
        }
    }
    // zero V pad keys 392..423
    for (int t = tid; t < HDIM * 32; t += 512) {
        int ch = t >> 5, k = t & 31;
        Vs[ch * VS_S + LTOK + k] = (__bf16)0.0f;
    }
    __syncthreads();

    __bf16* pb = Pb[wv];
    for (int tile = wv; tile < 25; tile += 8) {
        // ---- load Q fragment direct from f32 (scaled)
        int qrow = tile * 16 + lr;
        int qe = qrow < LTOK ? qrow : LTOK - 1;
        int tokq = (qe / 7) * WW + wi * WSP + qe % 7;
        const float* qp = qsrc + (size_t)tokq * CCH + lg * 8;
        f32x4 qa = *(const f32x4*)qp;
        f32x4 qc = *(const f32x4*)(qp + 4);
        bf16x8 aq;
#pragma unroll
        for (int i = 0; i < 4; i++) {
            aq[i] = (__bf16)(qa[i] * scale);
            aq[4 + i] = (__bf16)(qc[i] * scale);
        }

        // ---- S = Q K^T  (25 key tiles of 16)
        f32x4 s[26];
#pragma unroll
        for (int t = 0; t < 25; t++) {
            bf16x8 bk = *(const bf16x8*)&Ks[(t * 16 + lr) * KS_S + lg * 8];
            s[t] = __builtin_amdgcn_mfma_f32_16x16x32_bf16(
                aq, bk, (f32x4){0.f, 0.f, 0.f, 0.f}, 0, 0, 0);
        }
#pragma unroll
        for (int r = 0; r < 4; r++) s[25][r] = -INFINITY;
        if (lr >= 8) {
#pragma unroll
            for (int r = 0; r < 4; r++) s[24][r] = -INFINITY;   // keys 392..399
        }
        // ---- softmax (rows are (lg*4+r), reduce across lr lanes)
        float inv[4];
#pragma unroll
        for (int r = 0; r < 4; r++) {
            float m = s[0][r];
#pragma unroll
            for (int t = 1; t < 25; t++) m = fmaxf(m, s[t][r]);
#pragma unroll
            for (int off = 1; off < 16; off <<= 1) m = fmaxf(m, __shfl_xor(m, off, 64));
            float sum = 0.f;
#pragma unroll
            for (int t = 0; t < 26; t++) {
                float e = __expf(s[t][r] - m);
                s[t][r] = e;
                sum += e;
            }
#pragma unroll
            for (int off = 1; off < 16; off <<= 1) sum += __shfl_xor(sum, off, 64);
            inv[r] = 1.0f / sum;
        }
        // ---- PV: 13 chunks of 32 keys, per-wave LDS bounce for P transpose
        f32x4 xacc[2] = {{0.f, 0.f, 0.f, 0.f}, {0.f, 0.f, 0.f, 0.f}};
        for (int j = 0; j < 13; j++) {
#pragma unroll
            for (int half = 0; half < 2; half++) {
                int t = 2 * j + half;
#pragma unroll
                for (int r = 0; r < 4; r++)
                    pb[(lg * 4 + r) * PB_S + half * 16 + lr] = (__bf16)s[t][r];
            }
            asm volatile("s_waitcnt lgkmcnt(0)" ::: "memory");
            __builtin_amdgcn_sched_barrier(0);
            bf16x4 lo = *(const bf16x4*)&pb[lr * PB_S + lg * 8];
            bf16x4 hi = *(const bf16x4*)&pb[lr * PB_S + lg * 8 + 4];
            bf16x8 ap;
#pragma unroll
            for (int i = 0; i < 4; i++) { ap[i] = lo[i]; ap[4 + i] = hi[i]; }
#pragma unroll
            for (int nt = 0; nt < 2; nt++) {
                bf16x8 bv = *(const bf16x8*)&Vs[(nt * 16 + lr) * VS_S + j * 32 + lg * 8];
                xacc[nt] = __builtin_amdgcn_mfma_f32_16x16x32_bf16(ap, bv, xacc[nt], 0, 0, 0);
            }
            __builtin_amdgcn_sched_barrier(0);
        }
        // ---- write out (RMW add onto conv output)
#pragma unroll
        for (int r = 0; r < 4; r++) {
            int q = tile * 16 + lg * 4 + r;
            if (q < LTOK) {
                int rI = q / 7, c = q % 7;
                size_t base = ((size_t)b * NTOK + rI * WW + wi * WSP + c) * CCH + h * HDIM;
#pragma unroll
                for (int nt = 0; nt < 2; nt++)
                    out[base + nt * 16 + lr] += xacc[nt][r] * inv[r];
            }
        }
    }
}

// ---------------------------------------------------------------- launch
extern "C" void kernel_launch(void* const* d_in, const int* in_sizes, int n_in,
                              void* d_out, int out_size, void* d_ws, size_t ws_size,
                              hipStream_t stream) {
    const float* qkv = (const float*)d_in[0];
    const float* wconv = (const float*)d_in[1];
    const float* bconv = (const float*)d_in[2];
    float* out = (float*)d_out;
    char* ws = (char*)d_ws;

    const size_t WT_BYTES = (size_t)9 * CCH * CCH * 2;
    if (ws_size < WT_BYTES) return;
    __bf16* Wt = (__bf16*)ws;

    pack_w<<<(9 * CCH * CCH + 255) / 256, 256, 0, stream>>>(wconv, Wt);
    lepe_conv<<<NWIN * 7, 256, 0, stream>>>(qkv, Wt, bconv, out);
    attn2<<<NWIN * NHEADS, 512, 0, stream>>>(qkv, out);
}

// Round 4
// 193.218 us; speedup vs baseline: 1.8548x; 1.2854x over previous
//
#include <hip/hip_runtime.h>
#include <cmath>
#include <cstdint>

#define NBATCH 16
#define HH 56
#define WW 56
#define CCH 256
#define NHEADS 8
#define HDIM 32
#define WSP 7
#define NWIN 128
#define LTOK 392
#define NTOK 3136

typedef __attribute__((ext_vector_type(8))) __bf16 bf16x8;
typedef __attribute__((ext_vector_type(4))) __bf16 bf16x4;
typedef __attribute__((ext_vector_type(4))) float f32x4;

// ---------------------------------------------------------------- pack W
// HWIO (ky,kx,ci,co) fp32 -> [tap][co][ci] bf16 (contiguous ci for B-frags)
__global__ __launch_bounds__(256) void pack_w(const float* __restrict__ w,
                                              __bf16* __restrict__ Wt) {
    int idx = blockIdx.x * blockDim.x + threadIdx.x;
    if (idx >= 9 * CCH * CCH) return;
    int tap = idx / (CCH * CCH);
    int rem = idx % (CCH * CCH);
    int co = rem / CCH, ci = rem % CCH;
    Wt[idx] = (__bf16)(w[(size_t)tap * CCH * CCH + (size_t)ci * CCH + co]);
}

// ---------------------------------------------------------------- LePE conv
// Implicit GEMM. Block = (window, 8-row stripe): M=56 pos (padded 64), N=256.
// A: halo rows in LDS [10][9][264]. B: per-wave async global_load_lds pipeline,
// double-buffered per-wave 4KB LDS slots, counted vmcnt(4), no K-loop barriers.
// B LDS chunk-XOR swizzled (both sides: pre-permuted global src, swizzled read).
#define AV_R 10
#define AV_C 9
#define AV_S 264
__global__ __launch_bounds__(256, 2) void lepe_conv(const float* __restrict__ qkv,
        const __bf16* __restrict__ Wt, const float* __restrict__ bconv,
        float* __restrict__ out) {
    const int bid = blockIdx.x;
    const int win = bid / 7, rb = bid % 7;
    const int b = win >> 3, wi = win & 7;
    const int rbase = rb * 8;
    const int tid = threadIdx.x;
    const int lane = tid & 63, wv = tid >> 6;
    const int lr = lane & 15, lg = lane >> 4;
    __shared__ __bf16 Av[AV_R * AV_C * AV_S];   // 47,520 B
    __shared__ __bf16 Bs[2][4][2048];           // 32,768 B (2 bufs x 4 waves x 4KB)
    const float* vsrc = qkv + 2 * (size_t)NBATCH * NTOK * CCH;

    // ---- stage A (V window rows + halo), one fused pass, 8B LDS writes
    for (int t = tid; t < AV_R * AV_C * 64; t += 256) {
        int rr = t / (AV_C * 64);
        int rem = t % (AV_C * 64);
        int cc = rem / 64, chg = rem % 64;
        int ar = rbase + rr - 1, c = cc - 1;
        f32x4 v = {0.f, 0.f, 0.f, 0.f};
        if (ar >= 0 && ar < HH && c >= 0 && c < WSP) {
            int token = ar * WW + wi * WSP + c;
            v = *(const f32x4*)(vsrc + ((size_t)b * NTOK + token) * CCH + chg * 4);
        }
        bf16x4 w;
#pragma unroll
        for (int i = 0; i < 4; i++) w[i] = (__bf16)v[i];
        *(bf16x4*)&Av[(rr * AV_C + cc) * AV_S + chg * 4] = w;
    }
    __syncthreads();

    f32x4 acc[4][4];
#pragma unroll
    for (int i = 0; i < 4; i++)
#pragma unroll
        for (int j = 0; j < 4; j++) acc[i][j] = (f32x4){0.f, 0.f, 0.f, 0.f};

    // per-thread constant bases
    int ab[4];
#pragma unroll
    for (int mt = 0; mt < 4; mt++) {
        int p = mt * 16 + lr; if (p > 55) p = 55;
        ab[mt] = ((p / 7) * AV_C + (p % 7)) * AV_S + lg * 8;
    }
    // B frag LDS offsets (swizzled read): chunk = lg ^ ((lr>>1)&3)
    int bro[4];
#pragma unroll
    for (int nt = 0; nt < 4; nt++)
        bro[nt] = (nt * 16 + lr) * 32 + ((lg ^ ((lr >> 1) & 3)) * 8);
    // pre-permuted per-lane global source (write side of the swizzle)
    const __bf16* wsrc = Wt + (size_t)(wv * 64 + (lane >> 2)) * CCH
                            + (((lane & 3) ^ ((lane >> 3) & 3)) * 8);
    __bf16* b0 = &Bs[0][wv][0];
    __bf16* b1 = &Bs[1][wv][0];

#define GLDS(gp, lp)                                                        \
    __builtin_amdgcn_global_load_lds(                                       \
        (const __attribute__((address_space(1))) void*)(gp),                \
        (__attribute__((address_space(3))) void*)(lp), 16, 0, 0)
#define ISSUE(s, lb) do {                                                   \
        const int tp_ = (s) >> 3, kq_ = (s) & 7;                            \
        const __bf16* g_ = wsrc + tp_ * (CCH * CCH) + kq_ * 32;             \
        GLDS(g_, lb);                                                       \
        GLDS(g_ + 16 * CCH, (lb) + 512);                                    \
        GLDS(g_ + 32 * CCH, (lb) + 1024);                                   \
        GLDS(g_ + 48 * CCH, (lb) + 1536);                                   \
    } while (0)
#define STEPX(s, lb, doiss, s2) do {                                        \
        const int tap_ = (s) >> 3, ks_ = (s) & 7;                           \
        const int dy_ = (tap_ >= 6) ? 2 : ((tap_ >= 3) ? 1 : 0);            \
        const int offa = (tap_ + 6 * dy_) * AV_S + ks_ * 32;                \
        bf16x8 a_[4], bb_[4];                                               \
        _Pragma("unroll")                                                   \
        for (int mt = 0; mt < 4; mt++)                                      \
            a_[mt] = *(const bf16x8*)&Av[ab[mt] + offa];                    \
        _Pragma("unroll")                                                   \
        for (int nt = 0; nt < 4; nt++)                                      \
            bb_[nt] = *(const bf16x8*)&(lb)[bro[nt]];                       \
        asm volatile("s_waitcnt lgkmcnt(0)" ::: "memory");                  \
        __builtin_amdgcn_sched_barrier(0);                                  \
        if (doiss) ISSUE(s2, lb);                                           \
        _Pragma("unroll")                                                   \
        for (int mt = 0; mt < 4; mt++)                                      \
            _Pragma("unroll")                                               \
            for (int nt = 0; nt < 4; nt++)                                  \
                acc[mt][nt] = __builtin_amdgcn_mfma_f32_16x16x32_bf16(      \
                    a_[mt], bb_[nt], acc[mt][nt], 0, 0, 0);                 \
    } while (0)
#define WAIT4 asm volatile("s_waitcnt vmcnt(4)" ::: "memory")
#define WAIT0 asm volatile("s_waitcnt vmcnt(0)" ::: "memory")

    ISSUE(0, b0);
    ISSUE(1, b1);
    for (int s = 0; s < 70; s += 2) {
        WAIT4; STEPX(s, b0, 1, s + 2);
        WAIT4; STEPX(s + 1, b1, 1, s + 3);
    }
    WAIT4; STEPX(70, b0, 0, 0);
    WAIT0; STEPX(71, b1, 0, 0);
#undef GLDS
#undef ISSUE
#undef STEPX
#undef WAIT4
#undef WAIT0

#pragma unroll
    for (int nt = 0; nt < 4; nt++) {
        int ch = wv * 64 + nt * 16 + lr;
        float bias = bconv[ch];
#pragma unroll
        for (int mt = 0; mt < 4; mt++) {
#pragma unroll
            for (int r = 0; r < 4; r++) {
                int p = mt * 16 + lg * 4 + r;
                if (p < 56) {
                    int ar = rbase + p / 7, c = p % 7;
                    int token = ar * WW + wi * WSP + c;
                    out[((size_t)b * NTOK + token) * CCH + ch] = acc[mt][nt][r] + bias;
                }
            }
        }
    }
}

// ---------------------------------------------------------------- attention
// One block per (win, head). 8 waves. K (zero-padded to 400 rows) and V^T
// staged ONCE from f32 qkv with fused bf16 conversion; each wave sweeps
// q-tiles {wv, wv+8, wv+16, wv+24}. S in registers, softmax via shfl within
// 16-lane groups, P->A-frag via per-wave LDS bounce (stride 36, 2x b64 read).
#define KS_R 400
#define KS_S 36
#define VS_S 424
#define PB_S 36
__global__ __launch_bounds__(512, 4) void attn2(const float* __restrict__ qkv,
                                                float* __restrict__ out) {
    const int wh = blockIdx.x;
    const int win = wh >> 3, h = wh & 7;
    const int b = win >> 3, wi = win & 7;
    const int tid = threadIdx.x;
    const int lane = tid & 63, wv = tid >> 6;
    const int lr = lane & 15, lg = lane >> 4;
    const float scale = 0.17677669529663687f;   // 32^-0.5

    __shared__ __bf16 Ks[KS_R * KS_S];          // 28,800 B
    __shared__ __bf16 Vs[HDIM * VS_S];          // 27,136 B
    __shared__ __bf16 Pb[8][16 * PB_S];         //  9,216 B  (total 65,152)

    const size_t plane = (size_t)NBATCH * NTOK * CCH;
    const float* qsrc = qkv + ((size_t)b * NTOK) * CCH + h * HDIM;
    const float* ksrc = qsrc + plane;
    const float* vsrc = qsrc + 2 * plane;

    // ---- stage K: [400 rows][32 ch], rows >=392 zero
    for (int t = tid; t < KS_R * 4; t += 512) {
        int row = t >> 2, g = t & 3;
        bf16x8 val;
        if (row < LTOK) {
            int tok = (row / 7) * WW + wi * WSP + row % 7;
            const float* p = ksrc + (size_t)tok * CCH + g * 8;
            f32x4 a = *(const f32x4*)p;
            f32x4 c = *(const f32x4*)(p + 4);
#pragma unroll
            for (int i = 0; i < 4; i++) { val[i] = (__bf16)a[i]; val[4 + i] = (__bf16)c[i]; }
        } else {
#pragma unroll
            for (int i = 0; i < 8; i++) val[i] = (__bf16)0.0f;
        }
        *(bf16x8*)&Ks[row * KS_S + g * 8] = val;
    }
    // ---- stage V transposed: Vs[ch][key]
    for (int t = tid; t < LTOK * 4; t += 512) {
        int key = t % LTOK, chg = t / LTOK;
        int tok = (key / 7) * WW + wi * WSP + key % 7;
        const float* p = vsrc + (size_t)tok * CCH + chg * 8;
        f32x4 a = *(const f32x4*)p;
        f32x4 c = *(const f32x4*)(p + 4);
#pragma unroll
        for (int i = 0; i < 4; i++) {
            Vs[(chg * 8 + i) * VS_S + key] = (__bf16)a[i];
            Vs[(chg * 8 + 4 + i) * VS_S + key] = (__bf16)c[i];
        }
    }
    // zero V pad keys 392..423
    for (int t = tid; t < HDIM * 32; t += 512) {
        int ch = t >> 5, k = t & 31;
        Vs[ch * VS_S + LTOK + k] = (__bf16)0.0f;
    }
    __syncthreads();

    __bf16* pb = Pb[wv];
    for (int tile = wv; tile < 25; tile += 8) {
        // ---- load Q fragment direct from f32 (scaled)
        int qrow = tile * 16 + lr;
        int qe = qrow < LTOK ? qrow : LTOK - 1;
        int tokq = (qe / 7) * WW + wi * WSP + qe % 7;
        const float* qp = qsrc + (size_t)tokq * CCH + lg * 8;
        f32x4 qa = *(const f32x4*)qp;
        f32x4 qc = *(const f32x4*)(qp + 4);
        bf16x8 aq;
#pragma unroll
        for (int i = 0; i < 4; i++) {
            aq[i] = (__bf16)(qa[i] * scale);
            aq[4 + i] = (__bf16)(qc[i] * scale);
        }

        // ---- S = Q K^T  (25 key tiles of 16)
        f32x4 s[26];
#pragma unroll
        for (int t = 0; t < 25; t++) {
            bf16x8 bk = *(const bf16x8*)&Ks[(t * 16 + lr) * KS_S + lg * 8];
            s[t] = __builtin_amdgcn_mfma_f32_16x16x32_bf16(
                aq, bk, (f32x4){0.f, 0.f, 0.f, 0.f}, 0, 0, 0);
        }
#pragma unroll
        for (int r = 0; r < 4; r++) s[25][r] = -INFINITY;
        if (lr >= 8) {
#pragma unroll
            for (int r = 0; r < 4; r++) s[24][r] = -INFINITY;   // keys 392..399
        }
        // ---- softmax (rows are (lg*4+r), reduce across lr lanes)
        float inv[4];
#pragma unroll
        for (int r = 0; r < 4; r++) {
            float m = s[0][r];
#pragma unroll
            for (int t = 1; t < 25; t++) m = fmaxf(m, s[t][r]);
#pragma unroll
            for (int off = 1; off < 16; off <<= 1) m = fmaxf(m, __shfl_xor(m, off, 64));
            float sum = 0.f;
#pragma unroll
            for (int t = 0; t < 26; t++) {
                float e = __expf(s[t][r] - m);
                s[t][r] = e;
                sum += e;
            }
#pragma unroll
            for (int off = 1; off < 16; off <<= 1) sum += __shfl_xor(sum, off, 64);
            inv[r] = 1.0f / sum;
        }
        // ---- PV: 13 chunks of 32 keys, per-wave LDS bounce for P transpose
        f32x4 xacc[2] = {{0.f, 0.f, 0.f, 0.f}, {0.f, 0.f, 0.f, 0.f}};
        for (int j = 0; j < 13; j++) {
#pragma unroll
            for (int half = 0; half < 2; half++) {
                int t = 2 * j + half;
#pragma unroll
                for (int r = 0; r < 4; r++)
                    pb[(lg * 4 + r) * PB_S + half * 16 + lr] = (__bf16)s[t][r];
            }
            asm volatile("s_waitcnt lgkmcnt(0)" ::: "memory");
            __builtin_amdgcn_sched_barrier(0);
            bf16x4 lo = *(const bf16x4*)&pb[lr * PB_S + lg * 8];
            bf16x4 hi = *(const bf16x4*)&pb[lr * PB_S + lg * 8 + 4];
            bf16x8 ap;
#pragma unroll
            for (int i = 0; i < 4; i++) { ap[i] = lo[i]; ap[4 + i] = hi[i]; }
#pragma unroll
            for (int nt = 0; nt < 2; nt++) {
                bf16x8 bv = *(const bf16x8*)&Vs[(nt * 16 + lr) * VS_S + j * 32 + lg * 8];
                xacc[nt] = __builtin_amdgcn_mfma_f32_16x16x32_bf16(ap, bv, xacc[nt], 0, 0, 0);
            }
            __builtin_amdgcn_sched_barrier(0);
        }
        // ---- write out (RMW add onto conv output)
#pragma unroll
        for (int r = 0; r < 4; r++) {
            int q = tile * 16 + lg * 4 + r;
            if (q < LTOK) {
                int rI = q / 7, c = q % 7;
                size_t base = ((size_t)b * NTOK + rI * WW + wi * WSP + c) * CCH + h * HDIM;
#pragma unroll
                for (int nt = 0; nt < 2; nt++)
                    out[base + nt * 16 + lr] += xacc[nt][r] * inv[r];
            }
        }
    }
}

// ---------------------------------------------------------------- launch
extern "C" void kernel_launch(void* const* d_in, const int* in_sizes, int n_in,
                              void* d_out, int out_size, void* d_ws, size_t ws_size,
                              hipStream_t stream) {
    const float* qkv = (const float*)d_in[0];
    const float* wconv = (const float*)d_in[1];
    const float* bconv = (const float*)d_in[2];
    float* out = (float*)d_out;
    char* ws = (char*)d_ws;

    const size_t WT_BYTES = (size_t)9 * CCH * CCH * 2;
    if (ws_size < WT_BYTES) return;
    __bf16* Wt = (__bf16*)ws;

    pack_w<<<(9 * CCH * CCH + 255) / 256, 256, 0, stream>>>(wconv, Wt);
    lepe_conv<<<NWIN * 7, 256, 0, stream>>>(qkv, Wt, bconv, out);
    attn2<<<NWIN * NHEADS, 512, 0, stream>>>(qkv, out);
}